// Round 1
// baseline (207.889 us; speedup 1.0000x reference)
//
#include <hip/hip_runtime.h>

#define NN 100000
#define DEG 32
#define IN_DIM 25
#define AGG_DIM 75
#define OUT_DIM 128
#define NPB 10                 // nodes per block-iteration
#define NCHUNK (NN / NPB)      // 10000
#define BLK 256

// ws layout: bnbuf[0..127] = column sums of z, bnbuf[128..255] = column sum-of-squares
__global__ void zero_bn(float* bnbuf) {
    bnbuf[threadIdx.x] = 0.0f;   // 256 floats
}

__global__ __launch_bounds__(BLK) void pna_main(
    const float* __restrict__ h, const float* __restrict__ snorm,
    const int* __restrict__ esrc, const float* __restrict__ W,
    const float* __restrict__ b, float* __restrict__ z,
    float* __restrict__ bnbuf)
{
    __shared__ int   eids[NPB * DEG];        // 1.25 KB
    __shared__ float agg[NPB][AGG_DIM];      // 3 KB
    __shared__ float red[2 * BLK];           // 2 KB

    const int t = threadIdx.x;
    const int col  = t & 127;
    const int half = t >> 7;

    // W column held in registers: W is [75][128] row-major, col j contiguous across threads
    float wreg[AGG_DIM];
    #pragma unroll
    for (int k = 0; k < AGG_DIM; ++k) wreg[k] = W[k * OUT_DIM + col];
    const float bcol = b[col];

    const int nl_a = t / IN_DIM;             // aggregation node 0..9 (valid for t < 250)
    const int f    = t - nl_a * IN_DIM;      // feature 0..24

    float bns = 0.0f, bnq = 0.0f;

    for (int chunk = blockIdx.x; chunk < NCHUNK; chunk += gridDim.x) {
        const int n0 = chunk * NPB;
        __syncthreads();                      // phase-B reads of agg from prev iter done
        for (int i = t; i < NPB * DEG; i += BLK) eids[i] = esrc[n0 * DEG + i];
        __syncthreads();

        // ---- phase A: aggregate mean / max / std for 10 nodes (25 threads each) ----
        if (t < NPB * IN_DIM) {
            float s = 0.f, q = 0.f, m = -3.4e38f;
            #pragma unroll
            for (int e = 0; e < DEG; ++e) {
                const int src = eids[nl_a * DEG + e];
                const float v = h[src * IN_DIM + f];
                s += v; q += v * v; m = fmaxf(m, v);
            }
            const float mean = s * (1.0f / DEG);
            const float var  = fmaxf(q * (1.0f / DEG) - mean * mean, 0.0f);
            agg[nl_a][f]              = mean;
            agg[nl_a][IN_DIM + f]     = m;
            agg[nl_a][2 * IN_DIM + f] = sqrtf(var + 1e-5f);
        }
        __syncthreads();

        // ---- phase B: z = agg @ W + b, * snorm; accumulate BN partials ----
        #pragma unroll
        for (int p = 0; p < NPB / 2; ++p) {
            const int nl   = p * 2 + half;
            const int node = n0 + nl;
            float acc = bcol;
            #pragma unroll
            for (int k = 0; k < AGG_DIM; ++k) acc = fmaf(agg[nl][k], wreg[k], acc);
            acc *= snorm[node];
            z[node * OUT_DIM + col] = acc;
            bns += acc; bnq += acc * acc;
        }
    }

    // ---- block-level BN partial reduction, one atomic per column ----
    __syncthreads();
    red[t] = bns; red[BLK + t] = bnq;
    __syncthreads();
    if (t < OUT_DIM) {
        atomicAdd(&bnbuf[t],           red[t]       + red[t + 128]);
        atomicAdd(&bnbuf[OUT_DIM + t], red[BLK + t] + red[BLK + t + 128]);
    }
}

__global__ __launch_bounds__(BLK) void bn_apply(
    const float* __restrict__ bnbuf, const float* __restrict__ gamma,
    const float* __restrict__ beta, float* __restrict__ z)
{
    __shared__ float sc_s[OUT_DIM], sh_s[OUT_DIM];
    const int t = threadIdx.x;
    if (t < OUT_DIM) {
        const float mu = bnbuf[t] * (1.0f / NN);
        const float v  = fmaxf(bnbuf[OUT_DIM + t] * (1.0f / NN) - mu * mu, 0.0f);
        const float sc = gamma[t] * rsqrtf(v + 1e-5f);
        sc_s[t] = sc;
        sh_s[t] = beta[t] - mu * sc;
    }
    __syncthreads();
    const int c4 = (t & 31) * 4;             // column group fixed per thread
    const float s0 = sc_s[c4], s1 = sc_s[c4+1], s2 = sc_s[c4+2], s3 = sc_s[c4+3];
    const float h0 = sh_s[c4], h1 = sh_s[c4+1], h2 = sh_s[c4+2], h3 = sh_s[c4+3];

    float4* z4 = (float4*)z;
    const int total4 = NN * (OUT_DIM / 4);
    for (int i = blockIdx.x * BLK + t; i < total4; i += gridDim.x * BLK) {
        float4 v = z4[i];
        v.x = fmaxf(fmaf(v.x, s0, h0), 0.f);
        v.y = fmaxf(fmaf(v.y, s1, h1), 0.f);
        v.z = fmaxf(fmaf(v.z, s2, h2), 0.f);
        v.w = fmaxf(fmaf(v.w, s3, h3), 0.f);
        z4[i] = v;
    }
}

extern "C" void kernel_launch(void* const* d_in, const int* in_sizes, int n_in,
                              void* d_out, int out_size, void* d_ws, size_t ws_size,
                              hipStream_t stream) {
    const float* h     = (const float*)d_in[0];
    const float* snorm = (const float*)d_in[1];
    const int*   esrc  = (const int*)d_in[2];
    // d_in[3] = edge_dst: known structure repeat(arange(N), DEG) -> mailbox i is edges [32i, 32i+32)
    const float* W     = (const float*)d_in[4];
    const float* b     = (const float*)d_in[5];
    const float* gamma = (const float*)d_in[6];
    const float* beta  = (const float*)d_in[7];
    float* z     = (float*)d_out;
    float* bnbuf = (float*)d_ws;

    zero_bn<<<1, 256, 0, stream>>>(bnbuf);
    pna_main<<<2048, BLK, 0, stream>>>(h, snorm, esrc, W, b, z, bnbuf);
    bn_apply<<<2048, BLK, 0, stream>>>(bnbuf, gamma, beta, z);
}

// Round 2
// 192.389 us; speedup vs baseline: 1.0806x; 1.0806x over previous
//
#include <hip/hip_runtime.h>
#include <hip/hip_bf16.h>

#define NN 100000
#define DEG 32
#define IN_DIM 25
#define AGG_DIM 75
#define KPAD 104               // A-tile row stride (bf16): 16B-aligned, 2-way-bank-conflict only
#define OUT_DIM 128
#define NPB 10                 // nodes per chunk (M-tile is 16, rows 10..15 stay zero)
#define NCHUNK (NN / NPB)      // 10000
#define BLK 256
#define GRID 2048

typedef __attribute__((ext_vector_type(8))) short short8;   // bf16 MFMA A/B frag
typedef __attribute__((ext_vector_type(4))) float f32x4;    // MFMA C/D frag

static __device__ __forceinline__ ushort f2bf(float x) {
    __hip_bfloat16 h = __float2bfloat16(x);
    return *reinterpret_cast<ushort*>(&h);
}
static __device__ __forceinline__ float bf2f(ushort u) {
    return __uint_as_float(((unsigned)u) << 16);
}

// ws layout: [0..1023] bytes: bnbuf (256 floats); byte 1024+: h_bf16 (100000*25 ushorts = 5 MB)
__global__ __launch_bounds__(BLK) void prep(const float4* __restrict__ h4,
                                            ushort4* __restrict__ hb4,
                                            float* __restrict__ bnbuf) {
    int i = blockIdx.x * BLK + threadIdx.x;
    if (i < 2 * OUT_DIM) bnbuf[i] = 0.0f;
    const int total = NN * IN_DIM / 4;              // 625000
    for (; i < total; i += GRID * BLK) {
        float4 v = h4[i];
        ushort4 o;
        o.x = f2bf(v.x); o.y = f2bf(v.y); o.z = f2bf(v.z); o.w = f2bf(v.w);
        hb4[i] = o;
    }
}

__global__ __launch_bounds__(BLK) void pna_main(
    const ushort* __restrict__ hb, const float* __restrict__ snorm,
    const int* __restrict__ esrc, const float* __restrict__ W,
    const float* __restrict__ b, float* __restrict__ z,
    float* __restrict__ bnbuf)
{
    __shared__ ushort agg[16][KPAD];                // 3.25 KB, bf16 bits, A-tile

    const int t = threadIdx.x;
    const int lane = t & 63;
    const int wv = t >> 6;                          // wave 0..3 -> col tiles {2wv, 2wv+1}

    // zero A-tile once (rows 10..15 and k>=75 stay zero forever)
    for (int i = t; i < 16 * KPAD; i += BLK) ((ushort*)agg)[i] = 0;

    // ---- W fragments (B operand), loaded once into registers ----
    // B-frag[ct][kt]: lane holds W[kt*32 + (lane>>4)*8 + j][cb + (lane&15)], j=0..7
    const int cb0 = (wv * 2 + 0) * 16 + (lane & 15);
    const int cb1 = (wv * 2 + 1) * 16 + (lane & 15);
    short8 bfrag[2][3];
    #pragma unroll
    for (int ct = 0; ct < 2; ++ct) {
        const int cb = ct ? cb1 : cb0;
        #pragma unroll
        for (int kt = 0; kt < 3; ++kt) {
            short8 fr;
            #pragma unroll
            for (int j = 0; j < 8; ++j) {
                const int k = kt * 32 + ((lane >> 4) * 8) + j;
                const float w = (k < AGG_DIM) ? W[k * OUT_DIM + cb] : 0.0f;
                fr[j] = (short)f2bf(w);
            }
            bfrag[ct][kt] = fr;
        }
    }
    const float bb0 = b[cb0], bb1 = b[cb1];

    const int nl = t / IN_DIM;                      // aggregation node 0..9 (t<250)
    const int f  = t - nl * IN_DIM;                 // feature 0..24
    const bool aggthread = (t < NPB * IN_DIM);

    float bns0 = 0.f, bnq0 = 0.f, bns1 = 0.f, bnq1 = 0.f;

    for (int chunk = blockIdx.x; chunk < NCHUNK; chunk += GRID) {
        const int n0 = chunk * NPB;
        __syncthreads();                            // prev phase-B A-tile reads done
        // ---- phase A: gather + mean/max/std (25 threads per node) ----
        if (aggthread) {
            const int4* e4 = reinterpret_cast<const int4*>(esrc + (n0 + nl) * DEG);
            float s = 0.f, q = 0.f, m = -3.4e38f;
            #pragma unroll
            for (int eo = 0; eo < DEG / 4; ++eo) {
                const int4 ee = e4[eo];
                float v0 = bf2f(hb[ee.x * IN_DIM + f]);
                float v1 = bf2f(hb[ee.y * IN_DIM + f]);
                float v2 = bf2f(hb[ee.z * IN_DIM + f]);
                float v3 = bf2f(hb[ee.w * IN_DIM + f]);
                s += v0 + v1 + v2 + v3;
                q = fmaf(v0, v0, q); q = fmaf(v1, v1, q);
                q = fmaf(v2, v2, q); q = fmaf(v3, v3, q);
                m = fmaxf(m, fmaxf(fmaxf(v0, v1), fmaxf(v2, v3)));
            }
            const float mean = s * (1.0f / DEG);
            const float var  = fmaxf(q * (1.0f / DEG) - mean * mean, 0.0f);
            agg[nl][f]              = f2bf(mean);
            agg[nl][IN_DIM + f]     = f2bf(m);
            agg[nl][2 * IN_DIM + f] = f2bf(sqrtf(var + 1e-5f));
        }
        __syncthreads();

        // ---- phase B: MFMA z = agg @ W, + b, * snorm; BN partials ----
        const int arow = lane & 15;
        const int ak0  = (lane >> 4) * 8;
        f32x4 acc0 = {0.f, 0.f, 0.f, 0.f}, acc1 = {0.f, 0.f, 0.f, 0.f};
        #pragma unroll
        for (int kt = 0; kt < 3; ++kt) {
            const short8 afrag = *reinterpret_cast<const short8*>(&agg[arow][kt * 32 + ak0]);
            acc0 = __builtin_amdgcn_mfma_f32_16x16x32_bf16(afrag, bfrag[0][kt], acc0, 0, 0, 0);
            acc1 = __builtin_amdgcn_mfma_f32_16x16x32_bf16(afrag, bfrag[1][kt], acc1, 0, 0, 0);
        }
        const int r0 = (lane >> 4) * 4;
        #pragma unroll
        for (int r = 0; r < 4; ++r) {
            const int row = r0 + r;
            if (row < NPB) {
                const int node = n0 + row;
                const float sn = snorm[node];
                const float v0 = (acc0[r] + bb0) * sn;
                const float v1 = (acc1[r] + bb1) * sn;
                z[node * OUT_DIM + cb0] = v0;
                z[node * OUT_DIM + cb1] = v1;
                bns0 += v0; bnq0 = fmaf(v0, v0, bnq0);
                bns1 += v1; bnq1 = fmaf(v1, v1, bnq1);
            }
        }
    }

    // ---- BN partial reduction: lanes l, l+16, l+32, l+48 share a column ----
    bns0 += __shfl_xor(bns0, 16); bnq0 += __shfl_xor(bnq0, 16);
    bns0 += __shfl_xor(bns0, 32); bnq0 += __shfl_xor(bnq0, 32);
    bns1 += __shfl_xor(bns1, 16); bnq1 += __shfl_xor(bnq1, 16);
    bns1 += __shfl_xor(bns1, 32); bnq1 += __shfl_xor(bnq1, 32);
    if ((lane >> 4) == 0) {
        atomicAdd(&bnbuf[cb0], bns0);
        atomicAdd(&bnbuf[OUT_DIM + cb0], bnq0);
        atomicAdd(&bnbuf[cb1], bns1);
        atomicAdd(&bnbuf[OUT_DIM + cb1], bnq1);
    }
}

__global__ __launch_bounds__(BLK) void bn_apply(
    const float* __restrict__ bnbuf, const float* __restrict__ gamma,
    const float* __restrict__ beta, float* __restrict__ z)
{
    __shared__ float sc_s[OUT_DIM], sh_s[OUT_DIM];
    const int t = threadIdx.x;
    if (t < OUT_DIM) {
        const float mu = bnbuf[t] * (1.0f / NN);
        const float v  = fmaxf(bnbuf[OUT_DIM + t] * (1.0f / NN) - mu * mu, 0.0f);
        const float sc = gamma[t] * rsqrtf(v + 1e-5f);
        sc_s[t] = sc;
        sh_s[t] = beta[t] - mu * sc;
    }
    __syncthreads();
    const int c4 = (t & 31) * 4;
    const float s0 = sc_s[c4], s1 = sc_s[c4+1], s2 = sc_s[c4+2], s3 = sc_s[c4+3];
    const float h0 = sh_s[c4], h1 = sh_s[c4+1], h2 = sh_s[c4+2], h3 = sh_s[c4+3];

    float4* z4 = (float4*)z;
    const int total4 = NN * (OUT_DIM / 4);
    for (int i = blockIdx.x * BLK + t; i < total4; i += gridDim.x * BLK) {
        float4 v = z4[i];
        v.x = fmaxf(fmaf(v.x, s0, h0), 0.f);
        v.y = fmaxf(fmaf(v.y, s1, h1), 0.f);
        v.z = fmaxf(fmaf(v.z, s2, h2), 0.f);
        v.w = fmaxf(fmaf(v.w, s3, h3), 0.f);
        z4[i] = v;
    }
}

extern "C" void kernel_launch(void* const* d_in, const int* in_sizes, int n_in,
                              void* d_out, int out_size, void* d_ws, size_t ws_size,
                              hipStream_t stream) {
    const float* h     = (const float*)d_in[0];
    const float* snorm = (const float*)d_in[1];
    const int*   esrc  = (const int*)d_in[2];
    // d_in[3] = edge_dst: repeat(arange(N), DEG) -> mailbox i = edges [32i, 32i+32)
    const float* W     = (const float*)d_in[4];
    const float* b     = (const float*)d_in[5];
    const float* gamma = (const float*)d_in[6];
    const float* beta  = (const float*)d_in[7];
    float*  z     = (float*)d_out;
    float*  bnbuf = (float*)d_ws;
    ushort* hb    = (ushort*)((char*)d_ws + 1024);

    prep<<<GRID, BLK, 0, stream>>>((const float4*)h, (ushort4*)hb, bnbuf);
    pna_main<<<GRID, BLK, 0, stream>>>(hb, snorm, esrc, W, b, z, bnbuf);
    bn_apply<<<GRID, BLK, 0, stream>>>(bnbuf, gamma, beta, z);
}

// Round 4
// 186.158 us; speedup vs baseline: 1.1167x; 1.0335x over previous
//
#include <hip/hip_runtime.h>
#include <hip/hip_bf16.h>

#define NN 100000
#define DEG 32
#define IN_DIM 25
#define AGG_DIM 75
#define KPAD 104               // agg row stride (ushorts): 208 B = 13*16 -> b128-aligned
#define OUT_DIM 128
#define NPB 16                 // nodes per chunk == MFMA M-tile (fully used)
#define EPC (NPB * DEG)        // 512 edges per chunk
#define NCHUNK (NN / NPB)      // 6250
#define BLK 256
#define GRID 2048
#define PREP_GRID 391          // ceil(100000/256)

typedef __attribute__((ext_vector_type(8))) short short8;   // bf16 MFMA A/B frag
typedef __attribute__((ext_vector_type(4))) float f32x4;    // MFMA C/D frag

static __device__ __forceinline__ unsigned f2bf(float x) {
    __hip_bfloat16 h = __float2bfloat16(x);
    return (unsigned)*reinterpret_cast<unsigned short*>(&h);
}
static __device__ __forceinline__ float bflo(unsigned v) { return __uint_as_float(v << 16); }
static __device__ __forceinline__ float bfhi(unsigned v) { return __uint_as_float(v & 0xffff0000u); }

static __device__ __forceinline__ void gload16(const void* g, void* l) {
    __builtin_amdgcn_global_load_lds(
        (const __attribute__((address_space(1))) unsigned*)g,
        (__attribute__((address_space(3))) unsigned*)l, 16, 0, 0);
}

// ws layout: [0,1024) bnbuf (256 floats); [1024, 1024+6.4MB) h_bf16 padded [NN][32] ushorts
__global__ __launch_bounds__(BLK) void prep(const float* __restrict__ h,
                                            ushort* __restrict__ hbp,
                                            float* __restrict__ bnbuf) {
    const int t = threadIdx.x;
    const int gid = blockIdx.x * BLK + t;
    if (gid < 2 * OUT_DIM) bnbuf[gid] = 0.0f;
    for (int n = gid; n < NN; n += PREP_GRID * BLK) {
        const float* row = h + n * IN_DIM;
        unsigned u[16];
        #pragma unroll
        for (int k = 0; k < 12; ++k) u[k] = f2bf(row[2 * k]) | (f2bf(row[2 * k + 1]) << 16);
        u[12] = f2bf(row[24]);
        u[13] = 0u; u[14] = 0u; u[15] = 0u;
        uint4* dst = (uint4*)(hbp + (size_t)n * 32);
        dst[0] = make_uint4(u[0], u[1], u[2], u[3]);
        dst[1] = make_uint4(u[4], u[5], u[6], u[7]);
        dst[2] = make_uint4(u[8], u[9], u[10], u[11]);
        dst[3] = make_uint4(u[12], u[13], u[14], u[15]);
    }
}

__global__ __launch_bounds__(BLK) void pna_main(
    const ushort* __restrict__ hb, const float* __restrict__ snorm,
    const int* __restrict__ esrc, const float* __restrict__ W,
    const float* __restrict__ b, float* __restrict__ z,
    float* __restrict__ bnbuf)
{
    __shared__ __align__(1024) ushort E_s[EPC][32];   // 32 KB gathered edge rows (64B each)
    __shared__ int    ids_s[EPC];                     // 2 KB edge ids
    __shared__ ushort agg[NPB][KPAD];                 // 3.25 KB bf16 A-tile

    const int t = threadIdx.x;
    const int lane = t & 63;
    const int wv = t >> 6;

    // zero agg once (K-pad cols 75..103 stay zero forever)
    for (int i = t; i < NPB * KPAD; i += BLK) ((ushort*)agg)[i] = 0;

    // ---- W fragments (B operand), loaded once ----
    const int cb0 = (wv * 2 + 0) * 16 + (lane & 15);
    const int cb1 = (wv * 2 + 1) * 16 + (lane & 15);
    short8 bfrag[2][3];
    #pragma unroll
    for (int ct = 0; ct < 2; ++ct) {
        const int cb = ct ? cb1 : cb0;
        #pragma unroll
        for (int kt = 0; kt < 3; ++kt) {
            short8 fr;
            #pragma unroll
            for (int j = 0; j < 8; ++j) {
                const int k = kt * 32 + ((lane >> 4) * 8) + j;
                const float w = (k < AGG_DIM) ? W[k * OUT_DIM + cb] : 0.0f;
                fr[j] = (short)f2bf(w);
            }
            bfrag[ct][kt] = fr;
        }
    }
    const float bb0 = b[cb0], bb1 = b[cb1];

    // A1 constants: 4 lanes per row, 16B part each
    const int lsub = lane >> 2;          // row-within-group 0..15
    const int prt  = lane & 3;           // 16B part 0..3
    // A2 constants: 16 threads per node, dword-column f2 (covers features 2f2, 2f2+1)
    const int nl2 = t >> 4;              // node 0..15
    const int f2  = t & 15;              // active if < 13
    const bool a2act = (f2 < 13);
    const int dcol = f2 ^ ((nl2 & 3) << 2);   // XOR de-swizzle of stored dword index

    float bns0 = 0.f, bnq0 = 0.f, bns1 = 0.f, bnq1 = 0.f;

    for (int chunk = blockIdx.x; chunk < NCHUNK; chunk += GRID) {
        const int n0 = chunk * NPB;

        // ---- A0: stage 512 edge ids (coalesced 2 KB) ----
        ((int2*)ids_s)[t] = ((const int2*)(esrc + n0 * DEG))[t];
        __syncthreads();

        // ---- A1: row gather via global_load_lds (8 wave-instrs, 1 KB each) ----
        #pragma unroll
        for (int i = 0; i < 8; ++i) {
            const int g = wv * 8 + i;            // wave-uniform instr index 0..31
            const int r = g * 16 + lsub;         // edge row 0..511
            const int src = ids_s[r];
            const int psrc = prt ^ ((r >> 5) & 3);   // source-side XOR swizzle (dest linear)
            gload16((const char*)hb + ((size_t)src << 6) + (psrc << 4),
                    (char*)E_s + (g << 10));
        }
        __syncthreads();   // drains vmcnt: E_s ready

        // ---- A2: mean/max/std from LDS ----
        if (a2act) {
            const unsigned* Ew = (const unsigned*)E_s;
            const unsigned base = (unsigned)(nl2 * 512 + dcol);   // node row block (32 rows x 16 dw)
            float s0 = 0.f, q0 = 0.f, m0 = -3.4e38f;
            float s1 = 0.f, q1 = 0.f, m1 = -3.4e38f;
            #pragma unroll
            for (int e = 0; e < 32; ++e) {
                const int ee = (e + nl2) & 31;   // per-node rotation: bank spread + commutative
                const unsigned v = Ew[base + ee * 16];
                const float lo = bflo(v), hi = bfhi(v);
                s0 += lo; q0 = fmaf(lo, lo, q0); m0 = fmaxf(m0, lo);
                s1 += hi; q1 = fmaf(hi, hi, q1); m1 = fmaxf(m1, hi);
            }
            const float inv = 1.0f / DEG;
            const float mean0 = s0 * inv, var0 = fmaxf(q0 * inv - mean0 * mean0, 0.f);
            const float mean1 = s1 * inv, var1 = fmaxf(q1 * inv - mean1 * mean1, 0.f);
            const int ff = f2 * 2;
            agg[nl2][ff]              = (ushort)f2bf(mean0);
            agg[nl2][IN_DIM + ff]     = (ushort)f2bf(m0);
            agg[nl2][2 * IN_DIM + ff] = (ushort)f2bf(sqrtf(var0 + 1e-5f));
            if (ff + 1 < IN_DIM) {
                agg[nl2][ff + 1]              = (ushort)f2bf(mean1);
                agg[nl2][IN_DIM + ff + 1]     = (ushort)f2bf(m1);
                agg[nl2][2 * IN_DIM + ff + 1] = (ushort)f2bf(sqrtf(var1 + 1e-5f));
            }
        }
        __syncthreads();   // agg ready

        // ---- B: MFMA z = agg @ W, + b, * snorm; BN partials ----
        const int arow = lane & 15;
        const int ak0  = (lane >> 4) * 8;
        f32x4 acc0 = {0.f, 0.f, 0.f, 0.f}, acc1 = {0.f, 0.f, 0.f, 0.f};
        #pragma unroll
        for (int kt = 0; kt < 3; ++kt) {
            const short8 af = *reinterpret_cast<const short8*>(&agg[arow][kt * 32 + ak0]);
            acc0 = __builtin_amdgcn_mfma_f32_16x16x32_bf16(af, bfrag[0][kt], acc0, 0, 0, 0);
            acc1 = __builtin_amdgcn_mfma_f32_16x16x32_bf16(af, bfrag[1][kt], acc1, 0, 0, 0);
        }
        const int r0 = (lane >> 4) * 4;
        #pragma unroll
        for (int r = 0; r < 4; ++r) {
            const int node = n0 + r0 + r;
            const float sn = snorm[node];
            const float v0 = (acc0[r] + bb0) * sn;
            const float v1 = (acc1[r] + bb1) * sn;
            z[node * OUT_DIM + cb0] = v0;
            z[node * OUT_DIM + cb1] = v1;
            bns0 += v0; bnq0 = fmaf(v0, v0, bnq0);
            bns1 += v1; bnq1 = fmaf(v1, v1, bnq1);
        }
    }

    // ---- BN partial reduction: lanes l, l+16, l+32, l+48 share a column ----
    bns0 += __shfl_xor(bns0, 16); bnq0 += __shfl_xor(bnq0, 16);
    bns0 += __shfl_xor(bns0, 32); bnq0 += __shfl_xor(bnq0, 32);
    bns1 += __shfl_xor(bns1, 16); bnq1 += __shfl_xor(bnq1, 16);
    bns1 += __shfl_xor(bns1, 32); bnq1 += __shfl_xor(bnq1, 32);
    if ((lane >> 4) == 0) {
        atomicAdd(&bnbuf[cb0], bns0);
        atomicAdd(&bnbuf[OUT_DIM + cb0], bnq0);
        atomicAdd(&bnbuf[cb1], bns1);
        atomicAdd(&bnbuf[OUT_DIM + cb1], bnq1);
    }
}

__global__ __launch_bounds__(BLK) void bn_apply(
    const float* __restrict__ bnbuf, const float* __restrict__ gamma,
    const float* __restrict__ beta, float* __restrict__ z)
{
    __shared__ float sc_s[OUT_DIM], sh_s[OUT_DIM];
    const int t = threadIdx.x;
    if (t < OUT_DIM) {
        const float mu = bnbuf[t] * (1.0f / NN);
        const float v  = fmaxf(bnbuf[OUT_DIM + t] * (1.0f / NN) - mu * mu, 0.0f);
        const float sc = gamma[t] * rsqrtf(v + 1e-5f);
        sc_s[t] = sc;
        sh_s[t] = beta[t] - mu * sc;
    }
    __syncthreads();
    const int c4 = (t & 31) * 4;
    const float s0 = sc_s[c4], s1 = sc_s[c4+1], s2 = sc_s[c4+2], s3 = sc_s[c4+3];
    const float h0 = sh_s[c4], h1 = sh_s[c4+1], h2 = sh_s[c4+2], h3 = sh_s[c4+3];

    float4* z4 = (float4*)z;
    const int total4 = NN * (OUT_DIM / 4);
    for (int i = blockIdx.x * BLK + t; i < total4; i += gridDim.x * BLK) {
        float4 v = z4[i];
        v.x = fmaxf(fmaf(v.x, s0, h0), 0.f);
        v.y = fmaxf(fmaf(v.y, s1, h1), 0.f);
        v.z = fmaxf(fmaf(v.z, s2, h2), 0.f);
        v.w = fmaxf(fmaf(v.w, s3, h3), 0.f);
        z4[i] = v;
    }
}

extern "C" void kernel_launch(void* const* d_in, const int* in_sizes, int n_in,
                              void* d_out, int out_size, void* d_ws, size_t ws_size,
                              hipStream_t stream) {
    const float* h     = (const float*)d_in[0];
    const float* snorm = (const float*)d_in[1];
    const int*   esrc  = (const int*)d_in[2];
    // d_in[3] = edge_dst: repeat(arange(N), DEG) -> mailbox i = edges [32i, 32i+32)
    const float* W     = (const float*)d_in[4];
    const float* b     = (const float*)d_in[5];
    const float* gamma = (const float*)d_in[6];
    const float* beta  = (const float*)d_in[7];
    float*  z     = (float*)d_out;
    float*  bnbuf = (float*)d_ws;
    ushort* hbp   = (ushort*)((char*)d_ws + 1024);   // [NN][32] bf16, 6.4 MB

    prep<<<PREP_GRID, BLK, 0, stream>>>(h, hbp, bnbuf);
    pna_main<<<GRID, BLK, 0, stream>>>(hbp, snorm, esrc, W, b, z, bnbuf);
    bn_apply<<<2048, BLK, 0, stream>>>(bnbuf, gamma, beta, z);
}